// Round 3
// baseline (2696.627 us; speedup 1.0000x reference)
//
#include <hip/hip_runtime.h>
#include <hip/hip_bf16.h>

// Problem: B=4, N=2048, H=16, Dh=64, D=1024
// out = LN( softmax(Q K^T / 8) V @ W_out^T ) * g
// Dtype model (R1 NaN + R2 finite-garbage forensics): ALL fp32, in and out.
// Internal: attention fp32 vector math -> ws as bf16 -> bf16 MFMA projection
// with fp32 accumulate -> fp32 out -> LN fp32 in place.

#define Bv 4
#define Nv 2048
#define Hv 16
#define DHv 64
#define Dv 1024

typedef __attribute__((ext_vector_type(8))) short short8;
typedef __attribute__((ext_vector_type(4))) float floatx4;

__device__ inline unsigned pack_bf2(float a, float b) {
    unsigned short ua = __builtin_bit_cast(unsigned short, __float2bfloat16(a));
    unsigned short ub = __builtin_bit_cast(unsigned short, __float2bfloat16(b));
    return (unsigned)ua | ((unsigned)ub << 16);
}

// ---------------------------------------------------------------------------
// Stage 1: flash attention, fp32 in / fp32 math / bf16 out (ws, feeds MFMA).
// One thread = one query row. 128 threads/block. grid = (N/128, H, B).
// K/V tiles of 64 keys staged in LDS (fp32); all lanes broadcast-read.
// ---------------------------------------------------------------------------
__global__ __launch_bounds__(128)
void attn_kernel(const float* __restrict__ q,
                 const float* __restrict__ k,
                 const float* __restrict__ v,
                 __hip_bfloat16* __restrict__ out) {
    __shared__ __align__(16) float Kt[64 * 64];
    __shared__ __align__(16) float Vt[64 * 64];

    const int t = threadIdx.x;
    const int b = blockIdx.z, h = blockIdx.y;
    const int n = blockIdx.x * 128 + t;

    // Load and pre-scale Q row (scale = 1/sqrt(64) = 0.125).
    float qf[64];
    {
        const float4* qp = (const float4*)(q + ((size_t)(b * Nv + n)) * Dv + h * DHv);
#pragma unroll
        for (int i = 0; i < 16; ++i) {
            float4 u = qp[i];
            qf[i * 4 + 0] = u.x * 0.125f;
            qf[i * 4 + 1] = u.y * 0.125f;
            qf[i * 4 + 2] = u.z * 0.125f;
            qf[i * 4 + 3] = u.w * 0.125f;
        }
    }

    float acc[64];
#pragma unroll
    for (int d = 0; d < 64; ++d) acc[d] = 0.f;
    float m = -INFINITY, l = 0.f;

    for (int tile = 0; tile < Nv / 64; ++tile) {
        __syncthreads();
        // Stage 64 keys x 64 dims of K and V (4096 floats = 1024 float4 each).
#pragma unroll
        for (int i = 0; i < 8; ++i) {
            int idx = i * 128 + t;       // float4 index
            int r = idx >> 4;            // 16 float4 per row
            int c = (idx & 15) * 4;      // float column
            size_t g = ((size_t)(b * Nv + tile * 64 + r)) * Dv + h * DHv + c;
            ((float4*)Kt)[idx] = *(const float4*)(k + g);
            ((float4*)Vt)[idx] = *(const float4*)(v + g);
        }
        __syncthreads();

        for (int chunk = 0; chunk < 4; ++chunk) {
            float s[16];
#pragma unroll
            for (int j = 0; j < 16; ++j) {
                const float4* kr = (const float4*)(Kt + (chunk * 16 + j) * 64);
                float a0 = 0.f, a1 = 0.f, a2 = 0.f, a3 = 0.f;
#pragma unroll
                for (int dd = 0; dd < 16; ++dd) {
                    float4 f = kr[dd];
                    a0 += qf[4 * dd + 0] * f.x;
                    a1 += qf[4 * dd + 1] * f.y;
                    a2 += qf[4 * dd + 2] * f.z;
                    a3 += qf[4 * dd + 3] * f.w;
                }
                s[j] = (a0 + a1) + (a2 + a3);
            }
            float mx = m;
#pragma unroll
            for (int j = 0; j < 16; ++j) mx = fmaxf(mx, s[j]);
            float corr = __expf(m - mx);   // exp(-inf)=0 on first chunk
            m = mx;
            l *= corr;
#pragma unroll
            for (int d = 0; d < 64; ++d) acc[d] *= corr;
#pragma unroll
            for (int j = 0; j < 16; ++j) {
                float p = __expf(s[j] - m);
                l += p;
                const float4* vr = (const float4*)(Vt + (chunk * 16 + j) * 64);
#pragma unroll
                for (int dd = 0; dd < 16; ++dd) {
                    float4 f = vr[dd];
                    acc[4 * dd + 0] += p * f.x;
                    acc[4 * dd + 1] += p * f.y;
                    acc[4 * dd + 2] += p * f.z;
                    acc[4 * dd + 3] += p * f.w;
                }
            }
        }
    }

    float inv = 1.f / l;
    uint4* op = (uint4*)(out + ((size_t)(b * Nv + n)) * Dv + h * DHv);
#pragma unroll
    for (int i = 0; i < 8; ++i) {
        uint4 u;
        u.x = pack_bf2(acc[i * 8 + 0] * inv, acc[i * 8 + 1] * inv);
        u.y = pack_bf2(acc[i * 8 + 2] * inv, acc[i * 8 + 3] * inv);
        u.z = pack_bf2(acc[i * 8 + 4] * inv, acc[i * 8 + 5] * inv);
        u.w = pack_bf2(acc[i * 8 + 6] * inv, acc[i * 8 + 7] * inv);
        op[i] = u;
    }
}

// ---------------------------------------------------------------------------
// Stage 2: C = A @ W^T via MFMA bf16 (verified gemm_bt pattern), fp32 out.
// A: [8192,1024] bf16 (attn out, ws), W: [1024,1024] fp32 row-major ->
// converted to bf16 during LDS staging. C: fp32 pre-LN into d_out.
// Block tile 64x64, BK=32, 256 threads. LDS rows padded to 40 shorts
// (2-way bank aliasing only = free per m136).
// ---------------------------------------------------------------------------
__global__ __launch_bounds__(256)
void proj_kernel(const __hip_bfloat16* __restrict__ A,
                 const float* __restrict__ W,
                 float* __restrict__ C) {
    __shared__ __align__(16) short As[64 * 40];
    __shared__ __align__(16) short Ws[64 * 40];

    const int t = threadIdx.x;
    const int wave = t >> 6;
    const int lane = t & 63;
    const int quad = lane >> 4;
    const int lr = lane & 15;
    const int bm = blockIdx.y * 64;
    const int bn = blockIdx.x * 64;

    floatx4 acc[4] = {};

    const int sr = t >> 2;          // staging row 0..63
    const int sc = (t & 3) * 8;     // staging col 0,8,16,24

    for (int k0 = 0; k0 < Dv; k0 += 32) {
        __syncthreads();
        *(uint4*)&As[sr * 40 + sc] = *(const uint4*)(A + (size_t)(bm + sr) * Dv + k0 + sc);
        {
            const float* wp = W + (size_t)(bn + sr) * Dv + k0 + sc;
            float4 w0 = *(const float4*)(wp);
            float4 w1 = *(const float4*)(wp + 4);
            uint4 u;
            u.x = pack_bf2(w0.x, w0.y);
            u.y = pack_bf2(w0.z, w0.w);
            u.z = pack_bf2(w1.x, w1.y);
            u.w = pack_bf2(w1.z, w1.w);
            *(uint4*)&Ws[sr * 40 + sc] = u;
        }
        __syncthreads();

        short8 a = *(const short8*)&As[(wave * 16 + lr) * 40 + quad * 8];
#pragma unroll
        for (int tt = 0; tt < 4; ++tt) {
            short8 bf = *(const short8*)&Ws[(tt * 16 + lr) * 40 + quad * 8];
            acc[tt] = __builtin_amdgcn_mfma_f32_16x16x32_bf16(a, bf, acc[tt], 0, 0, 0);
        }
    }

    // C/D layout: col = lane&15, row = quad*4 + reg  [measured m89/m91]
#pragma unroll
    for (int tt = 0; tt < 4; ++tt) {
#pragma unroll
        for (int r = 0; r < 4; ++r) {
            int row = bm + wave * 16 + quad * 4 + r;
            int col = bn + tt * 16 + lr;
            C[(size_t)row * Dv + col] = acc[tt][r];
        }
    }
}

// ---------------------------------------------------------------------------
// Stage 3: LayerNorm in place on d_out (fp32). g is fp32.
// One block of 256 per row of 1024. Biased variance, eps=1e-5.
// ---------------------------------------------------------------------------
__global__ __launch_bounds__(256)
void ln_kernel(float* __restrict__ C,
               const float* __restrict__ g) {
    const int row = blockIdx.x;
    const int t = threadIdx.x;
    const int wave = t >> 6, lane = t & 63;

    float* rp = C + (size_t)row * Dv;
    float4 x = *(const float4*)(rp + t * 4);

    float s = x.x + x.y + x.z + x.w;
    float sq = x.x * x.x + x.y * x.y + x.z * x.z + x.w * x.w;
#pragma unroll
    for (int off = 32; off >= 1; off >>= 1) {
        s += __shfl_xor(s, off);
        sq += __shfl_xor(sq, off);
    }
    __shared__ float ss[4], ssq[4];
    if (lane == 0) { ss[wave] = s; ssq[wave] = sq; }
    __syncthreads();
    s = ss[0] + ss[1] + ss[2] + ss[3];
    sq = ssq[0] + ssq[1] + ssq[2] + ssq[3];

    const float rn = 1.f / (float)Dv;
    float mean = s * rn;
    float var = sq * rn - mean * mean;
    float inv = rsqrtf(var + 1e-5f);

    float4 gv = *(const float4*)(g + t * 4);

    float4 o;
    o.x = (x.x - mean) * inv * gv.x;
    o.y = (x.y - mean) * inv * gv.y;
    o.z = (x.z - mean) * inv * gv.z;
    o.w = (x.w - mean) * inv * gv.w;
    *(float4*)(rp + t * 4) = o;
}

// ---------------------------------------------------------------------------
extern "C" void kernel_launch(void* const* d_in, const int* in_sizes, int n_in,
                              void* d_out, int out_size, void* d_ws, size_t ws_size,
                              hipStream_t stream) {
    const float* q = (const float*)d_in[0];
    const float* k = (const float*)d_in[1];
    const float* v = (const float*)d_in[2];
    const float* W = (const float*)d_in[3];
    const float* g = (const float*)d_in[4];
    float* out = (float*)d_out;

    __hip_bfloat16* attn = (__hip_bfloat16*)d_ws;   // [8192,1024] bf16 = 16.8 MB

    attn_kernel<<<dim3(Nv / 128, Hv, Bv), 128, 0, stream>>>(q, k, v, attn);
    proj_kernel<<<dim3(Dv / 64, (Bv * Nv) / 64), 256, 0, stream>>>(attn, W, out);
    ln_kernel<<<Bv * Nv, 256, 0, stream>>>(out, g);
}

// Round 4
// 419.237 us; speedup vs baseline: 6.4322x; 6.4322x over previous
//
#include <hip/hip_runtime.h>
#include <hip/hip_bf16.h>

// Problem: B=4, N=2048, H=16, Dh=64, D=1024. All global tensors fp32;
// out = LN( softmax(Q K^T / 8) V @ W_out^T ) * g   (fp32 out).
// Stage 1: MFMA flash attention (bf16 compute, fp32 softmax state).
// Stage 2: bf16 MFMA projection (fp32 acc). Stage 3: fp32 LayerNorm.

#define Bv 4
#define Nv 2048
#define Hv 16
#define DHv 64
#define Dv 1024

typedef __attribute__((ext_vector_type(8))) short short8;
typedef __attribute__((ext_vector_type(4))) float floatx4;

__device__ inline unsigned pack_bf2(float a, float b) {
    unsigned short ua = __builtin_bit_cast(unsigned short, __float2bfloat16(a));
    unsigned short ub = __builtin_bit_cast(unsigned short, __float2bfloat16(b));
    return (unsigned)ua | ((unsigned)ub << 16);
}

// ---------------------------------------------------------------------------
// MFMA flash attention. Block = 256 thr (4 waves) = 64 queries of one (b,h).
// Wave w owns queries q0 + w*16 + lr (lr = lane&15).
// Per 64-key tile:
//   S^T = K·Q^T  (A-frag = K rows from LDS, B-frag = Q rows, regs)
//     -> C-layout: lane(quad,lr) holds S[q=lr][key=16tt+4quad+r], tt=0..3
//   online softmax: row = lr -> 15 in-lane + shfl_xor(16,32)
//   P -> A-operand layout by in-wave shuffle gather (quad permutation)
//   O += P·V (B-frag = V[key][d], 8 conflict-free scalar LDS reads, pad 66)
// ---------------------------------------------------------------------------
__global__ __launch_bounds__(256)
void attn_mfma(const float* __restrict__ q,
               const float* __restrict__ k,
               const float* __restrict__ v,
               __hip_bfloat16* __restrict__ out) {
    __shared__ __align__(16) short Qs[64 * 72];   // pad 72: aligned b128 frags
    __shared__ __align__(16) short Kt[64 * 72];
    __shared__ __align__(4)  short Vt[64 * 66];   // pad 66: conflict-free u16

    const int t = threadIdx.x;
    const int wave = t >> 6, lane = t & 63;
    const int quad = lane >> 4, lr = lane & 15;
    const int b = blockIdx.z, h = blockIdx.y;
    const int q0 = blockIdx.x * 64;
    const size_t bh = ((size_t)b * Nv) * Dv + h * DHv;  // + n*Dv per row

    // ---- stage Q (x 0.125, exact) ----
#pragma unroll
    for (int p = 0; p < 2; ++p) {
        int idx = p * 256 + t;
        int r = idx >> 3, c8 = idx & 7;
        const float4* src = (const float4*)(q + bh + (size_t)(q0 + r) * Dv + c8 * 8);
        float4 a = src[0], c = src[1];
        uint4 u;
        u.x = pack_bf2(a.x * 0.125f, a.y * 0.125f);
        u.y = pack_bf2(a.z * 0.125f, a.w * 0.125f);
        u.z = pack_bf2(c.x * 0.125f, c.y * 0.125f);
        u.w = pack_bf2(c.z * 0.125f, c.w * 0.125f);
        *(uint4*)&Qs[r * 72 + c8 * 8] = u;
    }
    __syncthreads();
    short8 qfrag[2];   // B-frag: Q[q = w*16+lr][d = 32*kh + 8*quad + j]
    qfrag[0] = *(const short8*)&Qs[(wave * 16 + lr) * 72 + quad * 8];
    qfrag[1] = *(const short8*)&Qs[(wave * 16 + lr) * 72 + 32 + quad * 8];

    floatx4 o_acc[4] = {};           // o_acc[td][r] = O[q=4quad+r][d=16td+lr]
    float mrow = -INFINITY, lrow = 0.f;

    const int srcA = ((2 * (quad & 1)) << 4) | lr;   // gather source lanes
    const int srcB = srcA + 16;

    for (int k0 = 0; k0 < Nv; k0 += 64) {
        __syncthreads();
        // stage K tile (rows = key, pad 72)
#pragma unroll
        for (int p = 0; p < 2; ++p) {
            int idx = p * 256 + t;
            int r = idx >> 3, c8 = idx & 7;
            const float4* src = (const float4*)(k + bh + (size_t)(k0 + r) * Dv + c8 * 8);
            float4 a = src[0], c = src[1];
            uint4 u;
            u.x = pack_bf2(a.x, a.y); u.y = pack_bf2(a.z, a.w);
            u.z = pack_bf2(c.x, c.y); u.w = pack_bf2(c.z, c.w);
            *(uint4*)&Kt[r * 72 + c8 * 8] = u;
        }
        // stage V tile (rows = key, pad 66, b32 writes)
#pragma unroll
        for (int p = 0; p < 2; ++p) {
            int idx = p * 256 + t;
            int r = idx >> 3, c8 = idx & 7;
            const float4* src = (const float4*)(v + bh + (size_t)(k0 + r) * Dv + c8 * 8);
            float4 a = src[0], c = src[1];
            unsigned* dst = (unsigned*)&Vt[r * 66 + c8 * 8];
            dst[0] = pack_bf2(a.x, a.y); dst[1] = pack_bf2(a.z, a.w);
            dst[2] = pack_bf2(c.x, c.y); dst[3] = pack_bf2(c.z, c.w);
        }
        __syncthreads();

        // ---- S^T = K·Q^T ----
        floatx4 s_acc[4] = {};
#pragma unroll
        for (int tt = 0; tt < 4; ++tt) {
            short8 kf0 = *(const short8*)&Kt[(tt * 16 + lr) * 72 + quad * 8];
            short8 kf1 = *(const short8*)&Kt[(tt * 16 + lr) * 72 + 32 + quad * 8];
            s_acc[tt] = __builtin_amdgcn_mfma_f32_16x16x32_bf16(kf0, qfrag[0], s_acc[tt], 0, 0, 0);
            s_acc[tt] = __builtin_amdgcn_mfma_f32_16x16x32_bf16(kf1, qfrag[1], s_acc[tt], 0, 0, 0);
        }

        // ---- online softmax (row = query lr, keys in-lane x quads) ----
        float tmax = -INFINITY;
#pragma unroll
        for (int tt = 0; tt < 4; ++tt)
#pragma unroll
            for (int r2 = 0; r2 < 4; ++r2) tmax = fmaxf(tmax, s_acc[tt][r2]);
        tmax = fmaxf(tmax, __shfl_xor(tmax, 16));
        tmax = fmaxf(tmax, __shfl_xor(tmax, 32));
        float mnew = fmaxf(mrow, tmax);
        float alpha = __expf(mrow - mnew);   // first tile: exp(-inf)=0
        mrow = mnew;
        float psum = 0.f;
#pragma unroll
        for (int tt = 0; tt < 4; ++tt)
#pragma unroll
            for (int r2 = 0; r2 < 4; ++r2) {
                float p = __expf(s_acc[tt][r2] - mnew);
                s_acc[tt][r2] = p;
                psum += p;
            }
        psum += __shfl_xor(psum, 16);
        psum += __shfl_xor(psum, 32);
        lrow = lrow * alpha + psum;

        // rescale O: lane's O rows are queries 4quad+r2 -> fetch their alpha
#pragma unroll
        for (int r2 = 0; r2 < 4; ++r2) {
            float ar = __shfl(alpha, quad * 4 + r2);
#pragma unroll
            for (int td = 0; td < 4; ++td) o_acc[td][r2] *= ar;
        }

        // pack P pairs: p2[tt*2+hh] = bf16(p[tt][2hh], p[tt][2hh+1])
        unsigned p2[8];
#pragma unroll
        for (int tt = 0; tt < 4; ++tt) {
            p2[tt * 2 + 0] = pack_bf2(s_acc[tt][0], s_acc[tt][1]);
            p2[tt * 2 + 1] = pack_bf2(s_acc[tt][2], s_acc[tt][3]);
        }

        // ---- PV: O += P·V ----
        bool hi = (quad >= 2);
#pragma unroll
        for (int kh = 0; kh < 2; ++kh) {
            // A-frag: P[q=lr][key = 32kh + 8quad + j] gathered from C-layout
            int tlo = (2 * kh) * 2, thi = (2 * kh + 1) * 2;
            unsigned d0a = __shfl(p2[tlo + 0], srcA), d0b = __shfl(p2[thi + 0], srcA);
            unsigned d1a = __shfl(p2[tlo + 1], srcA), d1b = __shfl(p2[thi + 1], srcA);
            unsigned d2a = __shfl(p2[tlo + 0], srcB), d2b = __shfl(p2[thi + 0], srcB);
            unsigned d3a = __shfl(p2[tlo + 1], srcB), d3b = __shfl(p2[thi + 1], srcB);
            int4 af;
            af.x = (int)(hi ? d0b : d0a);
            af.y = (int)(hi ? d1b : d1a);
            af.z = (int)(hi ? d2b : d2a);
            af.w = (int)(hi ? d3b : d3a);
            short8 afrag = __builtin_bit_cast(short8, af);
#pragma unroll
            for (int td = 0; td < 4; ++td) {
                short8 bfrag;
#pragma unroll
                for (int j = 0; j < 8; ++j)
                    bfrag[j] = Vt[(kh * 32 + quad * 8 + j) * 66 + td * 16 + lr];
                o_acc[td] = __builtin_amdgcn_mfma_f32_16x16x32_bf16(afrag, bfrag, o_acc[td], 0, 0, 0);
            }
        }
    }

    // ---- epilogue: O / l -> bf16 ws (proj A-matrix) ----
    float linv = 1.f / lrow;   // for query lr (replicated over quads)
#pragma unroll
    for (int r2 = 0; r2 < 4; ++r2) {
        float lv = __shfl(linv, quad * 4 + r2);
        int row = q0 + wave * 16 + quad * 4 + r2;
        size_t base = ((size_t)(b * Nv + row)) * Dv + h * DHv;
#pragma unroll
        for (int td = 0; td < 4; ++td)
            out[base + td * 16 + lr] = __float2bfloat16(o_acc[td][r2] * lv);
    }
}

// ---------------------------------------------------------------------------
// Stage 2: C = A @ W^T via MFMA bf16 (verified gemm_bt pattern), fp32 out.
// ---------------------------------------------------------------------------
__global__ __launch_bounds__(256)
void proj_kernel(const __hip_bfloat16* __restrict__ A,
                 const float* __restrict__ W,
                 float* __restrict__ C) {
    __shared__ __align__(16) short As[64 * 40];
    __shared__ __align__(16) short Ws[64 * 40];

    const int t = threadIdx.x;
    const int wave = t >> 6;
    const int lane = t & 63;
    const int quad = lane >> 4;
    const int lr = lane & 15;
    const int bm = blockIdx.y * 64;
    const int bn = blockIdx.x * 64;

    floatx4 acc[4] = {};

    const int sr = t >> 2;          // staging row 0..63
    const int sc = (t & 3) * 8;     // staging col 0,8,16,24

    for (int k0 = 0; k0 < Dv; k0 += 32) {
        __syncthreads();
        *(uint4*)&As[sr * 40 + sc] = *(const uint4*)(A + (size_t)(bm + sr) * Dv + k0 + sc);
        {
            const float* wp = W + (size_t)(bn + sr) * Dv + k0 + sc;
            float4 w0 = *(const float4*)(wp);
            float4 w1 = *(const float4*)(wp + 4);
            uint4 u;
            u.x = pack_bf2(w0.x, w0.y);
            u.y = pack_bf2(w0.z, w0.w);
            u.z = pack_bf2(w1.x, w1.y);
            u.w = pack_bf2(w1.z, w1.w);
            *(uint4*)&Ws[sr * 40 + sc] = u;
        }
        __syncthreads();

        short8 a = *(const short8*)&As[(wave * 16 + lr) * 40 + quad * 8];
#pragma unroll
        for (int tt = 0; tt < 4; ++tt) {
            short8 bf = *(const short8*)&Ws[(tt * 16 + lr) * 40 + quad * 8];
            acc[tt] = __builtin_amdgcn_mfma_f32_16x16x32_bf16(a, bf, acc[tt], 0, 0, 0);
        }
    }

    // C/D layout: col = lane&15, row = quad*4 + reg  [measured m89/m91]
#pragma unroll
    for (int tt = 0; tt < 4; ++tt) {
#pragma unroll
        for (int r = 0; r < 4; ++r) {
            int row = bm + wave * 16 + quad * 4 + r;
            int col = bn + tt * 16 + lr;
            C[(size_t)row * Dv + col] = acc[tt][r];
        }
    }
}

// ---------------------------------------------------------------------------
// Stage 3: LayerNorm in place on d_out (fp32). Biased variance, eps=1e-5.
// ---------------------------------------------------------------------------
__global__ __launch_bounds__(256)
void ln_kernel(float* __restrict__ C,
               const float* __restrict__ g) {
    const int row = blockIdx.x;
    const int t = threadIdx.x;
    const int wave = t >> 6, lane = t & 63;

    float* rp = C + (size_t)row * Dv;
    float4 x = *(const float4*)(rp + t * 4);

    float s = x.x + x.y + x.z + x.w;
    float sq = x.x * x.x + x.y * x.y + x.z * x.z + x.w * x.w;
#pragma unroll
    for (int off = 32; off >= 1; off >>= 1) {
        s += __shfl_xor(s, off);
        sq += __shfl_xor(sq, off);
    }
    __shared__ float ss[4], ssq[4];
    if (lane == 0) { ss[wave] = s; ssq[wave] = sq; }
    __syncthreads();
    s = ss[0] + ss[1] + ss[2] + ss[3];
    sq = ssq[0] + ssq[1] + ssq[2] + ssq[3];

    const float rn = 1.f / (float)Dv;
    float mean = s * rn;
    float var = sq * rn - mean * mean;
    float inv = rsqrtf(var + 1e-5f);

    float4 gv = *(const float4*)(g + t * 4);

    float4 o;
    o.x = (x.x - mean) * inv * gv.x;
    o.y = (x.y - mean) * inv * gv.y;
    o.z = (x.z - mean) * inv * gv.z;
    o.w = (x.w - mean) * inv * gv.w;
    *(float4*)(rp + t * 4) = o;
}

// ---------------------------------------------------------------------------
extern "C" void kernel_launch(void* const* d_in, const int* in_sizes, int n_in,
                              void* d_out, int out_size, void* d_ws, size_t ws_size,
                              hipStream_t stream) {
    const float* q = (const float*)d_in[0];
    const float* k = (const float*)d_in[1];
    const float* v = (const float*)d_in[2];
    const float* W = (const float*)d_in[3];
    const float* g = (const float*)d_in[4];
    float* out = (float*)d_out;

    __hip_bfloat16* attn = (__hip_bfloat16*)d_ws;   // [8192,1024] bf16 = 16.8 MB

    attn_mfma<<<dim3(Nv / 64, Hv, Bv), 256, 0, stream>>>(q, k, v, attn);
    proj_kernel<<<dim3(Dv / 64, (Bv * Nv) / 64), 256, 0, stream>>>(attn, W, out);
    ln_kernel<<<Bv * Nv, 256, 0, stream>>>(out, g);
}